// Round 10
// baseline (684.692 us; speedup 1.0000x reference)
//
#include <hip/hip_runtime.h>
#include <hip/hip_bf16.h>

using bf16 = __bf16;
using bf16x4 = __bf16 __attribute__((ext_vector_type(4)));
using bf16x8 = __bf16 __attribute__((ext_vector_type(8)));
using f32x4 = float __attribute__((ext_vector_type(4)));

static constexpr long ROWEL = 64L * 768;   // row stride of [B][N][*] tensors

// ---------------- patchify: x[b,3,128,128] -> flat bf16 [b][n][768] ----------------
__global__ __launch_bounds__(256) void k_patchify(const float* __restrict__ x, bf16* __restrict__ flat)
{
    const int n = blockIdx.x;      // patch 0..63
    const int b = blockIdx.y;      // batch 0..63
    const int i_ = n >> 3, j_ = n & 7;
    for (int it = 0; it < 3; ++it) {
        int f = threadIdx.x + it * 256;
        int c = f >> 8, rem = f & 255, pi = rem >> 4, pj = rem & 15;
        float v = x[(((long)(b * 3 + c)) << 14) + ((i_ * 16 + pi) << 7) + (j_ * 16 + pj)];
        flat[(long)b * ROWEL + n * 768 + f] = (bf16)v;
    }
}

// ---------------- merged cvt+transpose: z=0 w4 (3072x768), z=1 p1w (768x768) ----------------
__global__ __launch_bounds__(256) void k_cvt_t2(
    const float* __restrict__ W0, bf16* __restrict__ T0,
    const float* __restrict__ W1, bf16* __restrict__ T1)
{
    const int z = blockIdx.z;
    const float* W = z ? W1 : W0;
    bf16* Wt = z ? T1 : T0;
    const int Kd = z ? 768 : 3072, Nd = 768;
    if (z && blockIdx.x >= 12) return;
    __shared__ bf16 T[64 * 66];
    const int k0 = blockIdx.x * 64, n0 = blockIdx.y * 64;
    const int tid = threadIdx.x;
    const int kr = tid >> 4, nc = (tid & 15) * 4;
#pragma unroll
    for (int i = 0; i < 4; ++i) {
        f32x4 v = *(const f32x4*)(W + (long)(k0 + kr + i * 16) * Nd + n0 + nc);
#pragma unroll
        for (int e = 0; e < 4; ++e)
            T[(kr + i * 16) * 66 + nc + e] = (bf16)v[e];
    }
    __syncthreads();
    const int nr = tid >> 3, ks = (tid & 7) * 8;
#pragma unroll
    for (int it = 0; it < 2; ++it) {
        int n = nr + it * 32;
        bf16x8 o;
#pragma unroll
        for (int j = 0; j < 8; ++j) o[j] = T[(ks + j) * 66 + n];
        *(bf16x8*)(Wt + (long)(n0 + n) * Kd + k0 + ks) = o;
    }
}

// barrier without vmcnt drain: commit own LDS ops, raw barrier, pin schedule
__device__ __forceinline__ void barrier_lgkm()
{
    asm volatile("s_waitcnt lgkmcnt(0)" ::: "memory");
    __builtin_amdgcn_s_barrier();
    __builtin_amdgcn_sched_barrier(0);
}

// ---------------- reg-staged GEMM (bf16 A, bf16 Bt), depth-2: p1 + final ----------------
template<int BM, int BN>
__global__ __launch_bounds__(256) void k_gemm_rs(
    const bf16* __restrict__ A, long lda,
    const bf16* __restrict__ Bt, long ldb,
    int Ks,
    const float* __restrict__ bias,
    const float* __restrict__ addm,
    bf16* __restrict__ Cb, float* __restrict__ Cf, long ldc)
{
    constexpr int WM = BM / 2, WN = BN / 2, FM = WM / 16, FN = WN / 16;
    constexpr int NA = BM / 64, NB = BN / 64;
    __shared__ bf16 As[2][BM * 32];
    __shared__ bf16 Bs[2][BN * 32];
    const int tid = threadIdx.x, lane = tid & 63, wave = tid >> 6;
    const int wm = wave >> 1, wn = wave & 1;
    const long m0 = (long)blockIdx.x * BM, n0 = (long)blockIdx.y * BN;

    f32x4 acc[FM][FN];
#pragma unroll
    for (int i = 0; i < FM; ++i)
#pragma unroll
        for (int j = 0; j < FN; ++j) acc[i][j] = (f32x4){0.f, 0.f, 0.f, 0.f};

    const int nk = Ks >> 5;
    bf16x8 Xa[NA], Xb[NB], Ya[NA], Yb[NB];

    auto LOAD = [&](bf16x8 (&ra)[NA], bf16x8 (&rb)[NB], int kt) {
        const long kb = (long)kt * 32;
#pragma unroll
        for (int i = 0; i < NA; ++i) {
            const int c = i * 256 + tid, r = c >> 2, sg = c & 3;
            ra[i] = *(const bf16x8*)(A + (m0 + r) * lda + kb + sg * 8);
        }
#pragma unroll
        for (int i = 0; i < NB; ++i) {
            const int c = i * 256 + tid, r = c >> 2, sg = c & 3;
            rb[i] = *(const bf16x8*)(Bt + (n0 + r) * ldb + kb + sg * 8);
        }
    };
    auto WRITE = [&](bf16x8 (&ra)[NA], bf16x8 (&rb)[NB], int buf) {
#pragma unroll
        for (int i = 0; i < NA; ++i)
            *(bf16x8*)&As[buf][(i * 256 + tid) * 8] = ra[i];
#pragma unroll
        for (int i = 0; i < NB; ++i)
            *(bf16x8*)&Bs[buf][(i * 256 + tid) * 8] = rb[i];
    };
    auto COMPUTE = [&](int buf) {
        bf16x8 af[FM], bfr[FN];
#pragma unroll
        for (int i = 0; i < FM; ++i)
            af[i] = *(const bf16x8*)&As[buf][(wm * WM + i * 16 + (lane & 15)) * 32 + (lane >> 4) * 8];
#pragma unroll
        for (int j = 0; j < FN; ++j)
            bfr[j] = *(const bf16x8*)&Bs[buf][(wn * WN + j * 16 + (lane & 15)) * 32 + (lane >> 4) * 8];
#pragma unroll
        for (int i = 0; i < FM; ++i)
#pragma unroll
            for (int j = 0; j < FN; ++j)
                acc[i][j] = __builtin_amdgcn_mfma_f32_16x16x32_bf16(af[i], bfr[j], acc[i][j], 0, 0, 0);
    };

    LOAD(Xa, Xb, 0);
    LOAD(Ya, Yb, 1);
    WRITE(Xa, Xb, 0);
    barrier_lgkm();
    for (int t = 0; t < nk; t += 2) {
        if (t + 2 < nk) LOAD(Xa, Xb, t + 2);
        COMPUTE(0);
        if (t + 1 < nk) WRITE(Ya, Yb, 1);
        barrier_lgkm();
        if (t + 1 < nk) {
            if (t + 3 < nk) LOAD(Ya, Yb, t + 3);
            COMPUTE(1);
            if (t + 2 < nk) WRITE(Xa, Xb, 0);
            barrier_lgkm();
        }
    }

#pragma unroll
    for (int j = 0; j < FN; ++j) {
        const long col = n0 + wn * WN + j * 16 + (lane & 15);
        const float bb = bias ? bias[col] : 0.f;
#pragma unroll
        for (int i = 0; i < FM; ++i) {
#pragma unroll
            for (int r = 0; r < 4; ++r) {
                const long row = m0 + wm * WM + i * 16 + (lane >> 4) * 4 + r;
                const long idx = row * ldc + col;
                float v = acc[i][j][r] + bb;
                if (addm) v += addm[idx];
                if (Cb) Cb[idx] = (bf16)v;
                if (Cf) Cf[idx] = v;
            }
        }
    }
}

// ---------------- chain GEMM: A = bf16 OR sum of 3 fp32 partials; B = NATIVE fp32 rows [n][k] ----------------
// 1-D grid, XCD-grouped decode: all NX m-tiles of one (y,z) pair share an XCD (L2-shared B).
// Writes fp32 partials at bz*zstride.
template<bool ASUM>
__global__ __launch_bounds__(256) void k_chain(
    const bf16* __restrict__ Abf, const float* __restrict__ Ap, long apz, long lda,
    const float* __restrict__ Bf, long ldb,
    int Ks, int NX, int NY,
    float* __restrict__ Cp, long zstride, long ldc)
{
    constexpr int BM = 64, BN = 64;
    constexpr int WM = 32, WN = 32, FM = 2, FN = 2;
    __shared__ bf16 As[2][BM * 32];
    __shared__ bf16 Bs[2][BN * 32];
    const int tid = threadIdx.x, lane = tid & 63, wave = tid >> 6;
    const int wm = wave >> 1, wn = wave & 1;
    const int gid = blockIdx.x;
    const int xcd = gid & 7, mm = gid >> 3;
    const int bx = mm % NX, u = mm / NX;
    const int p = 8 * u + xcd;
    const int by = p % NY, bz = p / NY;
    const long m0 = (long)bx * BM, n0 = (long)by * BN;
    const long kofs = (long)bz * Ks;

    f32x4 acc[FM][FN];
#pragma unroll
    for (int i = 0; i < FM; ++i)
#pragma unroll
        for (int j = 0; j < FN; ++j) acc[i][j] = (f32x4){0.f, 0.f, 0.f, 0.f};

    const int nk = Ks >> 5;

    bf16x8 XaB, YaB;            // !ASUM A regs
    f32x4 Xa[2][3], Ya[2][3];   // ASUM A regs: 2 chunks x 3 partials
    f32x4 Xb[2], Yb[2];         // B regs: 2 chunks fp32

    auto LOAD = [&](bf16x8& raB, f32x4 (&ra)[2][3], f32x4 (&rb)[2], int kt) {
        const long kb = kofs + (long)kt * 32;
        if (ASUM) {
#pragma unroll
            for (int i = 0; i < 2; ++i) {
                const int c = i * 256 + tid, r = c >> 3, k4 = (c & 7) * 4;
#pragma unroll
                for (int z = 0; z < 3; ++z)
                    ra[i][z] = *(const f32x4*)(Ap + (long)z * apz + (m0 + r) * lda + kb + k4);
            }
        } else {
            const int r = tid >> 2, sg = tid & 3;
            raB = *(const bf16x8*)(Abf + (m0 + r) * lda + kb + sg * 8);
        }
#pragma unroll
        for (int i = 0; i < 2; ++i) {
            const int c = i * 256 + tid, n = c >> 3, k4 = (c & 7) * 4;
            rb[i] = *(const f32x4*)(Bf + (n0 + n) * ldb + kb + k4);
        }
    };
    auto WRITE = [&](bf16x8& raB, f32x4 (&ra)[2][3], f32x4 (&rb)[2], int buf) {
        if (ASUM) {
#pragma unroll
            for (int i = 0; i < 2; ++i) {
                const int c = i * 256 + tid, r = c >> 3, k4 = (c & 7) * 4;
                f32x4 s = ra[i][0] + ra[i][1] + ra[i][2];
                bf16x4 o;
#pragma unroll
                for (int e = 0; e < 4; ++e) o[e] = (bf16)s[e];
                *(bf16x4*)&As[buf][r * 32 + k4] = o;
            }
        } else {
            *(bf16x8*)&As[buf][tid * 8] = raB;
        }
#pragma unroll
        for (int i = 0; i < 2; ++i) {
            const int c = i * 256 + tid, n = c >> 3, k4 = (c & 7) * 4;
            bf16x4 o;
#pragma unroll
            for (int e = 0; e < 4; ++e) o[e] = (bf16)rb[i][e];
            *(bf16x4*)&Bs[buf][n * 32 + k4] = o;
        }
    };
    auto COMPUTE = [&](int buf) {
        bf16x8 af[FM], bfr[FN];
#pragma unroll
        for (int i = 0; i < FM; ++i)
            af[i] = *(const bf16x8*)&As[buf][(wm * WM + i * 16 + (lane & 15)) * 32 + (lane >> 4) * 8];
#pragma unroll
        for (int j = 0; j < FN; ++j)
            bfr[j] = *(const bf16x8*)&Bs[buf][(wn * WN + j * 16 + (lane & 15)) * 32 + (lane >> 4) * 8];
#pragma unroll
        for (int i = 0; i < FM; ++i)
#pragma unroll
            for (int j = 0; j < FN; ++j)
                acc[i][j] = __builtin_amdgcn_mfma_f32_16x16x32_bf16(af[i], bfr[j], acc[i][j], 0, 0, 0);
    };

    LOAD(XaB, Xa, Xb, 0);
    LOAD(YaB, Ya, Yb, 1);
    WRITE(XaB, Xa, Xb, 0);
    barrier_lgkm();
    for (int t = 0; t < nk; t += 2) {          // nk even at all call sites
        if (t + 2 < nk) LOAD(XaB, Xa, Xb, t + 2);
        COMPUTE(0);
        if (t + 1 < nk) WRITE(YaB, Ya, Yb, 1);
        barrier_lgkm();
        if (t + 1 < nk) {
            if (t + 3 < nk) LOAD(YaB, Ya, Yb, t + 3);
            COMPUTE(1);
            if (t + 2 < nk) WRITE(XaB, Xa, Xb, 0);
            barrier_lgkm();
        }
    }

    float* Cz = Cp + (long)bz * zstride;
#pragma unroll
    for (int j = 0; j < FN; ++j) {
        const long col = n0 + wn * WN + j * 16 + (lane & 15);
#pragma unroll
        for (int i = 0; i < FM; ++i)
#pragma unroll
            for (int r = 0; r < 4; ++r) {
                const long row = m0 + wm * WM + i * 16 + (lane >> 4) * 4 + r;
                Cz[row * ldc + col] = acc[i][j][r];
            }
    }
}

// ---------------- QKV: depth-4 reg pipeline, XCD-grouped grid (2304 blocks) ----------------
__global__ __launch_bounds__(256) void k_qkv(
    const bf16* __restrict__ flat,
    const float* __restrict__ Wq, const float* __restrict__ Wk, const float* __restrict__ Wv,
    const float* __restrict__ bq, const float* __restrict__ bk, const float* __restrict__ bv,
    bf16* __restrict__ qo, bf16* __restrict__ ko, bf16* __restrict__ vo)
{
    const int gid = blockIdx.x;
    const int xcd = gid & 7, mm = gid >> 3;
    const int nt = mm % 12, u = mm / 12;       // n-tile, group
    const int p = 8 * u + xcd;                 // (patch,proj) pair 0..191
    const int z = p >> 6;                      // proj 0..2
    const int zp = p & 63;                     // patch 0..63

    const float* W = z == 0 ? Wq : z == 1 ? Wk : Wv;
    const float* bias = z == 0 ? bq : z == 1 ? bk : bv;
    bf16* out = z == 0 ? qo : z == 1 ? ko : vo;

    __shared__ bf16 As[2][64 * 32];   // [b][k]
    __shared__ bf16 Bs[2][64 * 32];   // [n][k]
    const int tid = threadIdx.x, lane = tid & 63, wave = tid >> 6;
    const int wm = wave >> 1, wn = wave & 1;
    const int n0 = nt * 64;
    const float* Wz = W + (long)zp * 589824;

    f32x4 acc[2][2];
#pragma unroll
    for (int i = 0; i < 2; ++i)
#pragma unroll
        for (int j = 0; j < 2; ++j) acc[i][j] = (f32x4){0.f, 0.f, 0.f, 0.f};

    const int bcol = tid & 63;        // B col (n)
    const int bkg = (tid >> 6) * 8;   // B k-group
    bf16x8 A0, A1, A2, A3;
    float B0[8], B1[8], B2[8], B3[8];

    auto LOADQ = [&](bf16x8& ra, float (&rb)[8], int kt) {
        const int kb = kt * 32;
        const int r = tid >> 2, sg = tid & 3;
        ra = *(const bf16x8*)(flat + (long)r * ROWEL + zp * 768 + kb + sg * 8);
#pragma unroll
        for (int e = 0; e < 8; ++e)   // per e: 64 lanes read 256B contiguous
            rb[e] = Wz[(long)(kb + bkg + e) * 768 + n0 + bcol];
    };
    auto WRITEQ = [&](bf16x8& ra, float (&rb)[8], int buf) {
        *(bf16x8*)&As[buf][tid * 8] = ra;
        bf16x8 bb;
#pragma unroll
        for (int e = 0; e < 8; ++e) bb[e] = (bf16)rb[e];
        *(bf16x8*)&Bs[buf][bcol * 32 + bkg] = bb;
    };
    auto COMPUTEQ = [&](int buf) {
        bf16x8 af[2], bfr[2];
#pragma unroll
        for (int i = 0; i < 2; ++i)
            af[i] = *(const bf16x8*)&As[buf][(wm * 32 + i * 16 + (lane & 15)) * 32 + (lane >> 4) * 8];
#pragma unroll
        for (int j = 0; j < 2; ++j)
            bfr[j] = *(const bf16x8*)&Bs[buf][(wn * 32 + j * 16 + (lane & 15)) * 32 + (lane >> 4) * 8];
#pragma unroll
        for (int i = 0; i < 2; ++i)
#pragma unroll
            for (int j = 0; j < 2; ++j)
                acc[i][j] = __builtin_amdgcn_mfma_f32_16x16x32_bf16(af[i], bfr[j], acc[i][j], 0, 0, 0);
    };

    const int nk = 24;
    LOADQ(A0, B0, 0);
    LOADQ(A1, B1, 1);
    LOADQ(A2, B2, 2);
    WRITEQ(A0, B0, 0);
    barrier_lgkm();
    for (int t = 0; t < nk; t += 4) {
        if (t + 3 < nk) LOADQ(A3, B3, t + 3);
        COMPUTEQ(0);
        WRITEQ(A1, B1, 1);
        barrier_lgkm();
        if (t + 4 < nk) LOADQ(A0, B0, t + 4);
        COMPUTEQ(1);
        WRITEQ(A2, B2, 0);
        barrier_lgkm();
        if (t + 5 < nk) LOADQ(A1, B1, t + 5);
        COMPUTEQ(0);
        WRITEQ(A3, B3, 1);
        barrier_lgkm();
        if (t + 6 < nk) LOADQ(A2, B2, t + 6);
        COMPUTEQ(1);
        if (t + 4 < nk) WRITEQ(A0, B0, 0);
        barrier_lgkm();
    }

#pragma unroll
    for (int j = 0; j < 2; ++j) {
        const int col = n0 + wn * 32 + j * 16 + (lane & 15);
        const float bb = bias[zp * 768 + col];
#pragma unroll
        for (int i = 0; i < 2; ++i) {
#pragma unroll
            for (int r = 0; r < 4; ++r) {
                const int row = wm * 32 + i * 16 + (lane >> 4) * 4 + r;   // batch index
                out[(long)row * ROWEL + zp * 768 + col] = (bf16)(acc[i][j][r] + bb);
            }
        }
    }
}

// ---------------- sum 6 partials + p2w^T -> Mt bf16 (768x768) ----------------
__global__ __launch_bounds__(256) void k_skaddT(
    const float* __restrict__ P, long zstride, int S,
    const float* __restrict__ p2w, bf16* __restrict__ Mt)
{
    const int n = blockIdx.x;
    for (int k = threadIdx.x; k < 768; k += 256) {
        float s = p2w[(long)k * 768 + n];
        for (int z = 0; z < S; ++z) s += P[(long)z * zstride + n * 768 + k];
        Mt[n * 768 + k] = (bf16)s;
    }
}

// ---------------- bias chain step (fp32 weights) ----------------
__global__ __launch_bounds__(256) void k_vm2(
    const float* __restrict__ Pin, const float* __restrict__ bin, const float* __restrict__ W,
    int K, int N, float* __restrict__ Pout)
{
    __shared__ float red[4][64];
    const int tid = threadIdx.x;
    const int nl = tid & 63, kq = tid >> 6;
    const int n = blockIdx.x * 64 + nl;
    const int kc = blockIdx.y;
    const int kchunk = K / 8, kslice = kchunk / 4;
    const int k0 = kc * kchunk + kq * kslice;
    float acc = 0.f;
#pragma unroll 4
    for (int k = k0; k < k0 + kslice; ++k) {
        float vk = bin[k];
        if (Pin) {
#pragma unroll
            for (int j = 0; j < 8; ++j) vk += Pin[(long)j * K + k];
        }
        acc += vk * W[(long)k * N + n];
    }
    red[kq][nl] = acc;
    __syncthreads();
    if (kq == 0)
        Pout[(long)kc * N + n] = red[0][nl] + red[1][nl] + red[2][nl] + red[3][nl];
}

__global__ __launch_bounds__(256) void k_vred(
    const float* __restrict__ P, const float* __restrict__ b1, const float* __restrict__ b2,
    int N, float* __restrict__ out)
{
    const int n = blockIdx.x * 256 + threadIdx.x;
    if (n >= N) return;
    float s = b1[n] + (b2 ? b2[n] : 0.f);
#pragma unroll
    for (int j = 0; j < 8; ++j) s += P[(long)j * N + n];
    out[n] = s;
}

// ---------------- fused attention: grid (6 dc-chunks, 64 patches) ----------------
__global__ __launch_bounds__(256) void k_attn(
    const bf16* __restrict__ q, const bf16* __restrict__ k, const bf16* __restrict__ v,
    float* __restrict__ attn)
{
    const int dc = blockIdx.x;
    const int n = blockIdx.y;
    __shared__ bf16 QT[64 * 72];
    __shared__ bf16 KT[64 * 72];
    __shared__ float S[64 * 66];
    __shared__ bf16 P[64 * 72];
    __shared__ bf16 VT[128 * 72];

    const int tid = threadIdx.x, lane = tid & 63, wave = tid >> 6;
    const int wm = wave >> 1, wn = wave & 1;

    f32x4 accs[2][2];
#pragma unroll
    for (int i = 0; i < 2; ++i)
#pragma unroll
        for (int j = 0; j < 2; ++j) accs[i][j] = (f32x4){0.f, 0.f, 0.f, 0.f};

    for (int kt = 0; kt < 12; ++kt) {
#pragma unroll
        for (int i = 0; i < 2; ++i) {
            int cid = tid + i * 256;
            int r = cid >> 3, seg = cid & 7;
            *(bf16x8*)&QT[r * 72 + seg * 8] = *(const bf16x8*)(q + (long)r * ROWEL + n * 768 + kt * 64 + seg * 8);
            *(bf16x8*)&KT[r * 72 + seg * 8] = *(const bf16x8*)(k + (long)r * ROWEL + n * 768 + kt * 64 + seg * 8);
        }
        __syncthreads();
#pragma unroll
        for (int ks = 0; ks < 2; ++ks) {
            bf16x8 qa[2], kb2[2];
#pragma unroll
            for (int i = 0; i < 2; ++i)
                qa[i] = *(const bf16x8*)&QT[(wm * 32 + i * 16 + (lane & 15)) * 72 + ks * 32 + (lane >> 4) * 8];
#pragma unroll
            for (int j = 0; j < 2; ++j)
                kb2[j] = *(const bf16x8*)&KT[(wn * 32 + j * 16 + (lane & 15)) * 72 + ks * 32 + (lane >> 4) * 8];
#pragma unroll
            for (int i = 0; i < 2; ++i)
#pragma unroll
                for (int j = 0; j < 2; ++j)
                    accs[i][j] = __builtin_amdgcn_mfma_f32_16x16x32_bf16(qa[i], kb2[j], accs[i][j], 0, 0, 0);
        }
        __syncthreads();
    }
    const float sc = 0.03608439182435161f;
#pragma unroll
    for (int i = 0; i < 2; ++i)
#pragma unroll
        for (int j = 0; j < 2; ++j)
#pragma unroll
            for (int r = 0; r < 4; ++r)
                S[(wm * 32 + i * 16 + (lane >> 4) * 4 + r) * 66 + wn * 32 + j * 16 + (lane & 15)] = accs[i][j][r] * sc;
    __syncthreads();

    {
        int r = tid >> 2, l4 = tid & 3;
        float m = -1e30f;
        for (int c = l4; c < 64; c += 4) m = fmaxf(m, S[r * 66 + c]);
        m = fmaxf(m, __shfl_xor(m, 1));
        m = fmaxf(m, __shfl_xor(m, 2));
        float s = 0.f;
        for (int c = l4; c < 64; c += 4) { float e = __expf(S[r * 66 + c] - m); S[r * 66 + c] = e; s += e; }
        s += __shfl_xor(s, 1);
        s += __shfl_xor(s, 2);
        float inv = 1.f / s;
        for (int c = l4; c < 64; c += 4) P[r * 72 + c] = (bf16)(S[r * 66 + c] * inv);
    }
    __syncthreads();

    {
#pragma unroll
        for (int i = 0; i < 4; ++i) {
            int cid = tid + i * 256;
            int c = cid >> 4, seg = cid & 15;
            bf16x8 vv = *(const bf16x8*)(v + (long)c * ROWEL + n * 768 + dc * 128 + seg * 8);
#pragma unroll
            for (int e = 0; e < 8; ++e)
                VT[(seg * 8 + e) * 72 + c] = vv[e];
        }
        __syncthreads();
        f32x4 acco[2][4];
#pragma unroll
        for (int i = 0; i < 2; ++i)
#pragma unroll
            for (int j = 0; j < 4; ++j) acco[i][j] = (f32x4){0.f, 0.f, 0.f, 0.f};
#pragma unroll
        for (int ks = 0; ks < 2; ++ks) {
            bf16x8 pa[2], vb[4];
#pragma unroll
            for (int i = 0; i < 2; ++i)
                pa[i] = *(const bf16x8*)&P[(wm * 32 + i * 16 + (lane & 15)) * 72 + ks * 32 + (lane >> 4) * 8];
#pragma unroll
            for (int j = 0; j < 4; ++j)
                vb[j] = *(const bf16x8*)&VT[(wn * 64 + j * 16 + (lane & 15)) * 72 + ks * 32 + (lane >> 4) * 8];
#pragma unroll
            for (int i = 0; i < 2; ++i)
#pragma unroll
                for (int j = 0; j < 4; ++j)
                    acco[i][j] = __builtin_amdgcn_mfma_f32_16x16x32_bf16(pa[i], vb[j], acco[i][j], 0, 0, 0);
        }
#pragma unroll
        for (int i = 0; i < 2; ++i)
#pragma unroll
            for (int j = 0; j < 4; ++j)
#pragma unroll
                for (int r = 0; r < 4; ++r) {
                    long b = wm * 32 + i * 16 + (lane >> 4) * 4 + r;
                    int d = dc * 128 + wn * 64 + j * 16 + (lane & 15);
                    attn[b * ROWEL + n * 768 + d] = acco[i][j][r];
                }
    }
}

// ---------------- LayerNorm over last dim (768), in place ----------------
__global__ __launch_bounds__(256) void k_ln(float* __restrict__ a,
                                            const float* __restrict__ g, const float* __restrict__ bb)
{
    const long row = blockIdx.x * 4 + (threadIdx.x >> 6);
    const int lane = threadIdx.x & 63;
    float* p = a + row * 768;
    f32x4 xv[3];
    float s = 0.f;
#pragma unroll
    for (int c = 0; c < 3; ++c) {
        xv[c] = *(const f32x4*)(p + c * 256 + lane * 4);
        s += xv[c][0] + xv[c][1] + xv[c][2] + xv[c][3];
    }
#pragma unroll
    for (int o = 1; o < 64; o <<= 1) s += __shfl_xor(s, o);
    const float mu = s * (1.f / 768.f);
    float vs = 0.f;
#pragma unroll
    for (int c = 0; c < 3; ++c)
#pragma unroll
        for (int e = 0; e < 4; ++e) { float d = xv[c][e] - mu; vs += d * d; }
#pragma unroll
    for (int o = 1; o < 64; o <<= 1) vs += __shfl_xor(vs, o);
    const float rstd = rsqrtf(vs * (1.f / 768.f) + 1e-5f);
#pragma unroll
    for (int c = 0; c < 3; ++c)
#pragma unroll
        for (int e = 0; e < 4; ++e) {
            int col = c * 256 + lane * 4 + e;
            p[col] = (xv[c][e] - mu) * rstd * g[col] + bb[col];
        }
}

// ---------------- row softmax over 768, in place ----------------
__global__ __launch_bounds__(256) void k_softmax(float* __restrict__ o)
{
    const long row = blockIdx.x * 4 + (threadIdx.x >> 6);
    const int lane = threadIdx.x & 63;
    float* p = o + row * 768;
    f32x4 xv[3];
    float m = -1e30f;
#pragma unroll
    for (int c = 0; c < 3; ++c) {
        xv[c] = *(const f32x4*)(p + c * 256 + lane * 4);
        m = fmaxf(m, fmaxf(fmaxf(xv[c][0], xv[c][1]), fmaxf(xv[c][2], xv[c][3])));
    }
#pragma unroll
    for (int o2 = 1; o2 < 64; o2 <<= 1) m = fmaxf(m, __shfl_xor(m, o2));
    float s = 0.f;
#pragma unroll
    for (int c = 0; c < 3; ++c)
#pragma unroll
        for (int e = 0; e < 4; ++e) { float ev = __expf(xv[c][e] - m); xv[c][e] = ev; s += ev; }
#pragma unroll
    for (int o2 = 1; o2 < 64; o2 <<= 1) s += __shfl_xor(s, o2);
    const float inv = 1.f / s;
#pragma unroll
    for (int c = 0; c < 3; ++c)
        *(f32x4*)(p + c * 256 + lane * 4) = xv[c] * inv;
}

extern "C" void kernel_launch(void* const* d_in, const int* in_sizes, int n_in,
                              void* d_out, int out_size, void* d_ws, size_t ws_size,
                              hipStream_t stream)
{
    const float* x   = (const float*)d_in[0];
    const float* Wq  = (const float*)d_in[1];
    const float* bq  = (const float*)d_in[2];
    const float* Wk  = (const float*)d_in[3];
    const float* bk  = (const float*)d_in[4];
    const float* Wv  = (const float*)d_in[5];
    const float* bv  = (const float*)d_in[6];
    const float* lng = (const float*)d_in[7];
    const float* lnb = (const float*)d_in[8];
    const float* p1w = (const float*)d_in[9];
    const float* p1b = (const float*)d_in[10];
    const float* w0  = (const float*)d_in[11];
    const float* b0  = (const float*)d_in[12];
    const float* w1  = (const float*)d_in[13];
    const float* b1  = (const float*)d_in[14];
    const float* w2  = (const float*)d_in[15];
    const float* b2  = (const float*)d_in[16];
    const float* w3  = (const float*)d_in[17];
    const float* b3  = (const float*)d_in[18];
    const float* w4  = (const float*)d_in[19];
    const float* b4  = (const float*)d_in[20];
    const float* p2w = (const float*)d_in[21];
    const float* p2b = (const float*)d_in[22];
    float* out = (float*)d_out;

    char* wsbase = (char*)d_ws;
    size_t off = 0;
    auto alloc = [&](size_t bytes) { char* p = wsbase + off; off += (bytes + 255) & ~(size_t)255; return p; };
    bf16*  flat = (bf16*)alloc(4096L * 768 * 2);
    bf16*  qb   = (bf16*)alloc(4096L * 768 * 2);
    bf16*  kb   = (bf16*)alloc(4096L * 768 * 2);
    bf16*  vb2  = (bf16*)alloc(4096L * 768 * 2);
    float* attn = (float*)alloc(4096L * 768 * 4);
    bf16*  att  = (bf16*)alloc(4096L * 768 * 2);
    bf16*  p1t  = (bf16*)alloc(768L * 768 * 2);
    bf16*  w4t  = (bf16*)alloc(768L * 3072 * 2);
    bf16*  Mt   = (bf16*)alloc(768L * 768 * 2);
    float* Cpa  = (float*)alloc(3L * 768 * 3072 * 4);
    float* Cpb  = (float*)alloc(6L * 768 * 768 * 4 > 3L * 768 * 3072 * 4 ? 6L * 768 * 768 * 4 : 3L * 768 * 3072 * 4);
    float* vPa  = (float*)alloc(8L * 3072 * 4);
    float* vPb  = (float*)alloc(8L * 3072 * 4);
    float* c4   = (float*)alloc(768 * 4);
    if (off > ws_size) return;

    const long ZS  = 768L * 3072;    // partial stride steps 1-3
    const long ZS4 = 768L * 768;     // partial stride step 4

    // ---- prep ----
    k_patchify<<<dim3(64, 64), 256, 0, stream>>>(x, flat);
    k_cvt_t2<<<dim3(48, 12, 2), 256, 0, stream>>>(w4, w4t, p1w, p1t);

    // ---- QKV (XCD-grouped 1-D grid) ----
    k_qkv<<<2304, 256, 0, stream>>>(flat, Wq, Wk, Wv, bq, bk, bv, qb, kb, vb2);

    k_attn<<<dim3(6, 64), 256, 0, stream>>>(qb, kb, vb2, attn);
    k_ln<<<1024, 256, 0, stream>>>(attn, lng, lnb);
    // att = ln + flat @ p1_w + p1_b -> bf16
    k_gemm_rs<64, 64><<<dim3(64, 12), 256, 0, stream>>>(flat, 768, p1t, 768, 768, p1b, attn, att, nullptr, 768);

    // ---- weight collapse, fp32 weights direct, partial-sum A-loads ----
    // step1: Cpa[z] = (w4t . w3^T) partials          (A bf16, B = w3 native fp32)
    k_chain<false><<<1728, 256, 0, stream>>>(w4t, nullptr, 0, 3072, w3, 3072, 1024, 12, 48, Cpa, ZS, 3072);
    // step2: Cpb[z] = (sum(Cpa) . w2^T) partials
    k_chain<true><<<1728, 256, 0, stream>>>(nullptr, Cpa, ZS, 3072, w2, 3072, 1024, 12, 48, Cpb, ZS, 3072);
    // step3: Cpa[z] = (sum(Cpb) . w1^T) partials
    k_chain<true><<<1728, 256, 0, stream>>>(nullptr, Cpb, ZS, 3072, w1, 3072, 1024, 12, 48, Cpa, ZS, 3072);
    // step4: Cpb[z=0..5] = (sum(Cpa) . w0^T) partials (N=768)
    k_chain<true><<<864, 256, 0, stream>>>(nullptr, Cpa, ZS, 3072, w0, 3072, 512, 12, 12, Cpb, ZS4, 768);
    k_skaddT<<<768, 256, 0, stream>>>(Cpb, ZS4, 6, p2w, Mt);

    // ---- bias chain (fp32 weights) ----
    k_vm2<<<dim3(48, 8), 256, 0, stream>>>(nullptr, b0, w1, 3072, 3072, vPa);
    k_vm2<<<dim3(48, 8), 256, 0, stream>>>(vPa, b1, w2, 3072, 3072, vPb);
    k_vm2<<<dim3(48, 8), 256, 0, stream>>>(vPb, b2, w3, 3072, 3072, vPa);
    k_vm2<<<dim3(12, 8), 256, 0, stream>>>(vPa, b3, w4, 3072, 768, vPb);
    k_vred<<<3, 256, 0, stream>>>(vPb, b4, p2b, 768, c4);

    // ---- out = att @ (M + p2w) + c ----
    k_gemm_rs<64, 64><<<dim3(64, 12), 256, 0, stream>>>(att, 768, Mt, 768, 768, c4, nullptr, nullptr, out, 768);
    k_softmax<<<1024, 256, 0, stream>>>(out);
}

// Round 11
// 556.722 us; speedup vs baseline: 1.2299x; 1.2299x over previous
//
#include <hip/hip_runtime.h>
#include <hip/hip_bf16.h>

using bf16 = __bf16;
using bf16x4 = __bf16 __attribute__((ext_vector_type(4)));
using bf16x8 = __bf16 __attribute__((ext_vector_type(8)));
using f32x4 = float __attribute__((ext_vector_type(4)));

static constexpr long ROWEL = 64L * 768;   // row stride of [B][N][*] tensors

// ---------------- patchify: x[b,3,128,128] -> flat [b][n][768] AND flat_nb [n][b][768] ----------------
__global__ __launch_bounds__(256) void k_patchify(const float* __restrict__ x,
                                                  bf16* __restrict__ flat, bf16* __restrict__ flat_nb)
{
    const int n = blockIdx.x;      // patch 0..63
    const int b = blockIdx.y;      // batch 0..63
    const int i_ = n >> 3, j_ = n & 7;
    for (int it = 0; it < 3; ++it) {
        int f = threadIdx.x + it * 256;
        int c = f >> 8, rem = f & 255, pi = rem >> 4, pj = rem & 15;
        float v = x[(((long)(b * 3 + c)) << 14) + ((i_ * 16 + pi) << 7) + (j_ * 16 + pj)];
        bf16 o = (bf16)v;
        flat[(long)b * ROWEL + n * 768 + f] = o;
        flat_nb[(long)n * ROWEL + b * 768 + f] = o;
    }
}

// ---------------- merged cvt+transpose: z=0 w4 (3072x768), z=1 p1w (768x768) ----------------
__global__ __launch_bounds__(256) void k_cvt_t2(
    const float* __restrict__ W0, bf16* __restrict__ T0,
    const float* __restrict__ W1, bf16* __restrict__ T1)
{
    const int z = blockIdx.z;
    const float* W = z ? W1 : W0;
    bf16* Wt = z ? T1 : T0;
    const int Kd = z ? 768 : 3072, Nd = 768;
    if (z && blockIdx.x >= 12) return;
    __shared__ bf16 T[64 * 66];
    const int k0 = blockIdx.x * 64, n0 = blockIdx.y * 64;
    const int tid = threadIdx.x;
    const int kr = tid >> 4, nc = (tid & 15) * 4;
#pragma unroll
    for (int i = 0; i < 4; ++i) {
        f32x4 v = *(const f32x4*)(W + (long)(k0 + kr + i * 16) * Nd + n0 + nc);
#pragma unroll
        for (int e = 0; e < 4; ++e)
            T[(kr + i * 16) * 66 + nc + e] = (bf16)v[e];
    }
    __syncthreads();
    const int nr = tid >> 3, ks = (tid & 7) * 8;
#pragma unroll
    for (int it = 0; it < 2; ++it) {
        int n = nr + it * 32;
        bf16x8 o;
#pragma unroll
        for (int j = 0; j < 8; ++j) o[j] = T[(ks + j) * 66 + n];
        *(bf16x8*)(Wt + (long)(n0 + n) * Kd + k0 + ks) = o;
    }
}

// ---------------- merged fp32->bf16 casts: z selects w0..w3 ----------------
__global__ __launch_bounds__(256) void k_cast4(
    const float* __restrict__ s0, bf16* __restrict__ d0,
    const float* __restrict__ s1, bf16* __restrict__ d1,
    const float* __restrict__ s2, bf16* __restrict__ d2,
    const float* __restrict__ s3, bf16* __restrict__ d3)
{
    const int z = blockIdx.y;
    const float* W = z == 0 ? s0 : z == 1 ? s1 : z == 2 ? s2 : s3;
    bf16* o = z == 0 ? d0 : z == 1 ? d1 : z == 2 ? d2 : d3;
    const long nelem = z == 0 ? 768L * 3072 : 3072L * 3072;
    long i = ((long)blockIdx.x * 256 + threadIdx.x) * 8;
    if (i >= nelem) return;
    f32x4 a = *(const f32x4*)(W + i);
    f32x4 b = *(const f32x4*)(W + i + 4);
    bf16x8 v;
#pragma unroll
    for (int e = 0; e < 4; ++e) { v[e] = (bf16)a[e]; v[4 + e] = (bf16)b[e]; }
    *(bf16x8*)(o + i) = v;
}

// barrier without vmcnt drain: commit own LDS ops, raw barrier, pin schedule
__device__ __forceinline__ void barrier_lgkm()
{
    asm volatile("s_waitcnt lgkmcnt(0)" ::: "memory");
    __builtin_amdgcn_s_barrier();
    __builtin_amdgcn_sched_barrier(0);
}

// ---------------- reg-staged GEMM (bf16 A, bf16 Bt), depth-2: p1 + final ----------------
template<int BM, int BN>
__global__ __launch_bounds__(256) void k_gemm_rs(
    const bf16* __restrict__ A, long lda,
    const bf16* __restrict__ Bt, long ldb,
    int Ks,
    const float* __restrict__ bias,
    const float* __restrict__ addm,
    bf16* __restrict__ Cb, float* __restrict__ Cf, long ldc)
{
    constexpr int WM = BM / 2, WN = BN / 2, FM = WM / 16, FN = WN / 16;
    constexpr int NA = BM / 64, NB = BN / 64;
    __shared__ bf16 As[2][BM * 32];
    __shared__ bf16 Bs[2][BN * 32];
    const int tid = threadIdx.x, lane = tid & 63, wave = tid >> 6;
    const int wm = wave >> 1, wn = wave & 1;
    const long m0 = (long)blockIdx.x * BM, n0 = (long)blockIdx.y * BN;

    f32x4 acc[FM][FN];
#pragma unroll
    for (int i = 0; i < FM; ++i)
#pragma unroll
        for (int j = 0; j < FN; ++j) acc[i][j] = (f32x4){0.f, 0.f, 0.f, 0.f};

    const int nk = Ks >> 5;
    bf16x8 Xa[NA], Xb[NB], Ya[NA], Yb[NB];

    auto LOAD = [&](bf16x8 (&ra)[NA], bf16x8 (&rb)[NB], int kt) {
        const long kb = (long)kt * 32;
#pragma unroll
        for (int i = 0; i < NA; ++i) {
            const int c = i * 256 + tid, r = c >> 2, sg = c & 3;
            ra[i] = *(const bf16x8*)(A + (m0 + r) * lda + kb + sg * 8);
        }
#pragma unroll
        for (int i = 0; i < NB; ++i) {
            const int c = i * 256 + tid, r = c >> 2, sg = c & 3;
            rb[i] = *(const bf16x8*)(Bt + (n0 + r) * ldb + kb + sg * 8);
        }
    };
    auto WRITE = [&](bf16x8 (&ra)[NA], bf16x8 (&rb)[NB], int buf) {
#pragma unroll
        for (int i = 0; i < NA; ++i)
            *(bf16x8*)&As[buf][(i * 256 + tid) * 8] = ra[i];
#pragma unroll
        for (int i = 0; i < NB; ++i)
            *(bf16x8*)&Bs[buf][(i * 256 + tid) * 8] = rb[i];
    };
    auto COMPUTE = [&](int buf) {
        bf16x8 af[FM], bfr[FN];
#pragma unroll
        for (int i = 0; i < FM; ++i)
            af[i] = *(const bf16x8*)&As[buf][(wm * WM + i * 16 + (lane & 15)) * 32 + (lane >> 4) * 8];
#pragma unroll
        for (int j = 0; j < FN; ++j)
            bfr[j] = *(const bf16x8*)&Bs[buf][(wn * WN + j * 16 + (lane & 15)) * 32 + (lane >> 4) * 8];
#pragma unroll
        for (int i = 0; i < FM; ++i)
#pragma unroll
            for (int j = 0; j < FN; ++j)
                acc[i][j] = __builtin_amdgcn_mfma_f32_16x16x32_bf16(af[i], bfr[j], acc[i][j], 0, 0, 0);
    };

    LOAD(Xa, Xb, 0);
    LOAD(Ya, Yb, 1);
    WRITE(Xa, Xb, 0);
    barrier_lgkm();
    for (int t = 0; t < nk; t += 2) {
        if (t + 2 < nk) LOAD(Xa, Xb, t + 2);
        COMPUTE(0);
        if (t + 1 < nk) WRITE(Ya, Yb, 1);
        barrier_lgkm();
        if (t + 1 < nk) {
            if (t + 3 < nk) LOAD(Ya, Yb, t + 3);
            COMPUTE(1);
            if (t + 2 < nk) WRITE(Xa, Xb, 0);
            barrier_lgkm();
        }
    }

#pragma unroll
    for (int j = 0; j < FN; ++j) {
        const long col = n0 + wn * WN + j * 16 + (lane & 15);
        const float bb = bias ? bias[col] : 0.f;
#pragma unroll
        for (int i = 0; i < FM; ++i) {
#pragma unroll
            for (int r = 0; r < 4; ++r) {
                const long row = m0 + wm * WM + i * 16 + (lane >> 4) * 4 + r;
                const long idx = row * ldc + col;
                float v = acc[i][j][r] + bb;
                if (addm) v += addm[idx];
                if (Cb) Cb[idx] = (bf16)v;
                if (Cf) Cf[idx] = v;
            }
        }
    }
}

// ---------------- chain GEMM (distinct name for profiling): bf16 A, bf16 Bt, split-K partials ----------------
__global__ __launch_bounds__(256) void k_chainrs(
    const bf16* __restrict__ A, long lda,
    const bf16* __restrict__ Bt, long ldb,
    int Ks,
    float* __restrict__ Cp, long zstride, long ldc)
{
    __shared__ bf16 As[2][64 * 32];
    __shared__ bf16 Bs[2][64 * 32];
    const int tid = threadIdx.x, lane = tid & 63, wave = tid >> 6;
    const int wm = wave >> 1, wn = wave & 1;
    const long m0 = (long)blockIdx.x * 64, n0 = (long)blockIdx.y * 64;
    const long kofs = (long)blockIdx.z * Ks;

    f32x4 acc[2][2];
#pragma unroll
    for (int i = 0; i < 2; ++i)
#pragma unroll
        for (int j = 0; j < 2; ++j) acc[i][j] = (f32x4){0.f, 0.f, 0.f, 0.f};

    const int nk = Ks >> 5;
    bf16x8 Xa, Xb, Ya, Yb;

    auto LOAD = [&](bf16x8& ra, bf16x8& rb, int kt) {
        const long kb = kofs + (long)kt * 32;
        const int r = tid >> 2, sg = tid & 3;
        ra = *(const bf16x8*)(A + (m0 + r) * lda + kb + sg * 8);
        rb = *(const bf16x8*)(Bt + (n0 + r) * ldb + kb + sg * 8);
    };
    auto WRITE = [&](bf16x8& ra, bf16x8& rb, int buf) {
        *(bf16x8*)&As[buf][tid * 8] = ra;
        *(bf16x8*)&Bs[buf][tid * 8] = rb;
    };
    auto COMPUTE = [&](int buf) {
        bf16x8 af[2], bfr[2];
#pragma unroll
        for (int i = 0; i < 2; ++i)
            af[i] = *(const bf16x8*)&As[buf][(wm * 32 + i * 16 + (lane & 15)) * 32 + (lane >> 4) * 8];
#pragma unroll
        for (int j = 0; j < 2; ++j)
            bfr[j] = *(const bf16x8*)&Bs[buf][(wn * 32 + j * 16 + (lane & 15)) * 32 + (lane >> 4) * 8];
#pragma unroll
        for (int i = 0; i < 2; ++i)
#pragma unroll
            for (int j = 0; j < 2; ++j)
                acc[i][j] = __builtin_amdgcn_mfma_f32_16x16x32_bf16(af[i], bfr[j], acc[i][j], 0, 0, 0);
    };

    LOAD(Xa, Xb, 0);
    LOAD(Ya, Yb, 1);
    WRITE(Xa, Xb, 0);
    barrier_lgkm();
    for (int t = 0; t < nk; t += 2) {
        if (t + 2 < nk) LOAD(Xa, Xb, t + 2);
        COMPUTE(0);
        if (t + 1 < nk) WRITE(Ya, Yb, 1);
        barrier_lgkm();
        if (t + 1 < nk) {
            if (t + 3 < nk) LOAD(Ya, Yb, t + 3);
            COMPUTE(1);
            if (t + 2 < nk) WRITE(Xa, Xb, 0);
            barrier_lgkm();
        }
    }

    float* Cz = Cp + (long)blockIdx.z * zstride;
#pragma unroll
    for (int j = 0; j < 2; ++j) {
        const long col = n0 + wn * 32 + j * 16 + (lane & 15);
#pragma unroll
        for (int i = 0; i < 2; ++i)
#pragma unroll
            for (int r = 0; r < 4; ++r) {
                const long row = m0 + wm * 32 + i * 16 + (lane >> 4) * 4 + r;
                Cz[row * ldc + col] = acc[i][j][r];
            }
    }
}

// ---------------- QKV: depth-2 reg pipeline (R9 body), XCD-grouped 1-D grid, patch-major A ----------------
__global__ __launch_bounds__(256) void k_qkv(
    const bf16* __restrict__ flat_nb,
    const float* __restrict__ Wq, const float* __restrict__ Wk, const float* __restrict__ Wv,
    const float* __restrict__ bq, const float* __restrict__ bk, const float* __restrict__ bv,
    bf16* __restrict__ qo, bf16* __restrict__ ko, bf16* __restrict__ vo)
{
    const int gid = blockIdx.x;
    const int xcd = gid & 7, mm = gid >> 3;
    const int nt = mm % 12, u = mm / 12;       // n-tile, group 0..23
    const int p = 8 * u + xcd;                 // (patch,proj) 0..191
    const int z = p >> 6;                      // proj
    const int zp = p & 63;                     // patch

    const float* W = z == 0 ? Wq : z == 1 ? Wk : Wv;
    const float* bias = z == 0 ? bq : z == 1 ? bk : bv;
    bf16* out = z == 0 ? qo : z == 1 ? ko : vo;

    __shared__ bf16 As[2][64 * 32];   // [b][k]
    __shared__ bf16 Bs[2][64 * 32];   // [n][k]
    const int tid = threadIdx.x, lane = tid & 63, wave = tid >> 6;
    const int wm = wave >> 1, wn = wave & 1;
    const int n0 = nt * 64;
    const float* Wz = W + (long)zp * 589824;
    const bf16* Az = flat_nb + (long)zp * ROWEL;   // [b][768] contiguous 96KB

    f32x4 acc[2][2];
#pragma unroll
    for (int i = 0; i < 2; ++i)
#pragma unroll
        for (int j = 0; j < 2; ++j) acc[i][j] = (f32x4){0.f, 0.f, 0.f, 0.f};

    const int bcol = tid & 63;        // B col (n)
    const int bkg = (tid >> 6) * 8;   // B k-group
    bf16x8 Xa, Ya;
    float Xb[8], Yb[8];

    auto LOADQ = [&](bf16x8& ra, float (&rb)[8], int kt) {
        const int kb = kt * 32;
        const int r = tid >> 2, sg = tid & 3;
        ra = *(const bf16x8*)(Az + (long)r * 768 + kb + sg * 8);
#pragma unroll
        for (int e = 0; e < 8; ++e)   // per e: 64 lanes read 256B contiguous
            rb[e] = Wz[(long)(kb + bkg + e) * 768 + n0 + bcol];
    };
    auto WRITEQ = [&](bf16x8& ra, float (&rb)[8], int buf) {
        *(bf16x8*)&As[buf][tid * 8] = ra;
        bf16x8 bb;
#pragma unroll
        for (int e = 0; e < 8; ++e) bb[e] = (bf16)rb[e];
        *(bf16x8*)&Bs[buf][bcol * 32 + bkg] = bb;
    };
    auto COMPUTEQ = [&](int buf) {
        bf16x8 af[2], bfr[2];
#pragma unroll
        for (int i = 0; i < 2; ++i)
            af[i] = *(const bf16x8*)&As[buf][(wm * 32 + i * 16 + (lane & 15)) * 32 + (lane >> 4) * 8];
#pragma unroll
        for (int j = 0; j < 2; ++j)
            bfr[j] = *(const bf16x8*)&Bs[buf][(wn * 32 + j * 16 + (lane & 15)) * 32 + (lane >> 4) * 8];
#pragma unroll
        for (int i = 0; i < 2; ++i)
#pragma unroll
            for (int j = 0; j < 2; ++j)
                acc[i][j] = __builtin_amdgcn_mfma_f32_16x16x32_bf16(af[i], bfr[j], acc[i][j], 0, 0, 0);
    };

    const int nk = 24;
    LOADQ(Xa, Xb, 0);
    LOADQ(Ya, Yb, 1);
    WRITEQ(Xa, Xb, 0);
    barrier_lgkm();
    for (int t = 0; t < nk; t += 2) {
        if (t + 2 < nk) LOADQ(Xa, Xb, t + 2);
        COMPUTEQ(0);
        if (t + 1 < nk) WRITEQ(Ya, Yb, 1);
        barrier_lgkm();
        if (t + 1 < nk) {
            if (t + 3 < nk) LOADQ(Ya, Yb, t + 3);
            COMPUTEQ(1);
            if (t + 2 < nk) WRITEQ(Xa, Xb, 0);
            barrier_lgkm();
        }
    }

#pragma unroll
    for (int j = 0; j < 2; ++j) {
        const int col = n0 + wn * 32 + j * 16 + (lane & 15);
        const float bb = bias[zp * 768 + col];
#pragma unroll
        for (int i = 0; i < 2; ++i) {
#pragma unroll
            for (int r = 0; r < 4; ++r) {
                const int row = wm * 32 + i * 16 + (lane >> 4) * 4 + r;   // batch index
                out[(long)row * ROWEL + zp * 768 + col] = (bf16)(acc[i][j][r] + bb);
            }
        }
    }
}

// ---------------- sum S split-K partials -> bf16 ----------------
__global__ __launch_bounds__(256) void k_skadd(
    const float* __restrict__ P, long zstride, int S, long nelem, bf16* __restrict__ out)
{
    long i = ((long)blockIdx.x * 256 + threadIdx.x) * 4;
    if (i >= nelem) return;
    f32x4 s = *(const f32x4*)(P + i);
    for (int z = 1; z < S; ++z) {
        f32x4 p = *(const f32x4*)(P + (long)z * zstride + i);
        s += p;
    }
    bf16x4 o;
#pragma unroll
    for (int e = 0; e < 4; ++e) o[e] = (bf16)s[e];
    *(bf16x4*)(out + i) = o;
}

// ---------------- sum S partials + p2w^T -> Mt bf16 (768x768) ----------------
__global__ __launch_bounds__(256) void k_skaddT(
    const float* __restrict__ P, long zstride, int S,
    const float* __restrict__ p2w, bf16* __restrict__ Mt)
{
    const int n = blockIdx.x;
    for (int k = threadIdx.x; k < 768; k += 256) {
        float s = p2w[(long)k * 768 + n];
        for (int z = 0; z < S; ++z) s += P[(long)z * zstride + n * 768 + k];
        Mt[n * 768 + k] = (bf16)s;
    }
}

// ---------------- bias chain step ----------------
template<typename TW>
__global__ __launch_bounds__(256) void k_vm2(
    const float* __restrict__ Pin, const float* __restrict__ bin, const TW* __restrict__ W,
    int K, int N, float* __restrict__ Pout)
{
    __shared__ float red[4][64];
    const int tid = threadIdx.x;
    const int nl = tid & 63, kq = tid >> 6;
    const int n = blockIdx.x * 64 + nl;
    const int kc = blockIdx.y;
    const int kchunk = K / 8, kslice = kchunk / 4;
    const int k0 = kc * kchunk + kq * kslice;
    float acc = 0.f;
#pragma unroll 4
    for (int k = k0; k < k0 + kslice; ++k) {
        float vk = bin[k];
        if (Pin) {
#pragma unroll
            for (int j = 0; j < 8; ++j) vk += Pin[(long)j * K + k];
        }
        acc += vk * (float)W[(long)k * N + n];
    }
    red[kq][nl] = acc;
    __syncthreads();
    if (kq == 0)
        Pout[(long)kc * N + n] = red[0][nl] + red[1][nl] + red[2][nl] + red[3][nl];
}

__global__ __launch_bounds__(256) void k_vred(
    const float* __restrict__ P, const float* __restrict__ b1, const float* __restrict__ b2,
    int N, float* __restrict__ out)
{
    const int n = blockIdx.x * 256 + threadIdx.x;
    if (n >= N) return;
    float s = b1[n] + (b2 ? b2[n] : 0.f);
#pragma unroll
    for (int j = 0; j < 8; ++j) s += P[(long)j * N + n];
    out[n] = s;
}

// ---------------- fused attention: grid (6 dc-chunks, 64 patches) ----------------
__global__ __launch_bounds__(256) void k_attn(
    const bf16* __restrict__ q, const bf16* __restrict__ k, const bf16* __restrict__ v,
    float* __restrict__ attn)
{
    const int dc = blockIdx.x;
    const int n = blockIdx.y;
    __shared__ bf16 QT[64 * 72];
    __shared__ bf16 KT[64 * 72];
    __shared__ float S[64 * 66];
    __shared__ bf16 P[64 * 72];
    __shared__ bf16 VT[128 * 72];

    const int tid = threadIdx.x, lane = tid & 63, wave = tid >> 6;
    const int wm = wave >> 1, wn = wave & 1;

    f32x4 accs[2][2];
#pragma unroll
    for (int i = 0; i < 2; ++i)
#pragma unroll
        for (int j = 0; j < 2; ++j) accs[i][j] = (f32x4){0.f, 0.f, 0.f, 0.f};

    for (int kt = 0; kt < 12; ++kt) {
#pragma unroll
        for (int i = 0; i < 2; ++i) {
            int cid = tid + i * 256;
            int r = cid >> 3, seg = cid & 7;
            *(bf16x8*)&QT[r * 72 + seg * 8] = *(const bf16x8*)(q + (long)r * ROWEL + n * 768 + kt * 64 + seg * 8);
            *(bf16x8*)&KT[r * 72 + seg * 8] = *(const bf16x8*)(k + (long)r * ROWEL + n * 768 + kt * 64 + seg * 8);
        }
        __syncthreads();
#pragma unroll
        for (int ks = 0; ks < 2; ++ks) {
            bf16x8 qa[2], kb2[2];
#pragma unroll
            for (int i = 0; i < 2; ++i)
                qa[i] = *(const bf16x8*)&QT[(wm * 32 + i * 16 + (lane & 15)) * 72 + ks * 32 + (lane >> 4) * 8];
#pragma unroll
            for (int j = 0; j < 2; ++j)
                kb2[j] = *(const bf16x8*)&KT[(wn * 32 + j * 16 + (lane & 15)) * 72 + ks * 32 + (lane >> 4) * 8];
#pragma unroll
            for (int i = 0; i < 2; ++i)
#pragma unroll
                for (int j = 0; j < 2; ++j)
                    accs[i][j] = __builtin_amdgcn_mfma_f32_16x16x32_bf16(qa[i], kb2[j], accs[i][j], 0, 0, 0);
        }
        __syncthreads();
    }
    const float sc = 0.03608439182435161f;
#pragma unroll
    for (int i = 0; i < 2; ++i)
#pragma unroll
        for (int j = 0; j < 2; ++j)
#pragma unroll
            for (int r = 0; r < 4; ++r)
                S[(wm * 32 + i * 16 + (lane >> 4) * 4 + r) * 66 + wn * 32 + j * 16 + (lane & 15)] = accs[i][j][r] * sc;
    __syncthreads();

    {
        int r = tid >> 2, l4 = tid & 3;
        float m = -1e30f;
        for (int c = l4; c < 64; c += 4) m = fmaxf(m, S[r * 66 + c]);
        m = fmaxf(m, __shfl_xor(m, 1));
        m = fmaxf(m, __shfl_xor(m, 2));
        float s = 0.f;
        for (int c = l4; c < 64; c += 4) { float e = __expf(S[r * 66 + c] - m); S[r * 66 + c] = e; s += e; }
        s += __shfl_xor(s, 1);
        s += __shfl_xor(s, 2);
        float inv = 1.f / s;
        for (int c = l4; c < 64; c += 4) P[r * 72 + c] = (bf16)(S[r * 66 + c] * inv);
    }
    __syncthreads();

    {
#pragma unroll
        for (int i = 0; i < 4; ++i) {
            int cid = tid + i * 256;
            int c = cid >> 4, seg = cid & 15;
            bf16x8 vv = *(const bf16x8*)(v + (long)c * ROWEL + n * 768 + dc * 128 + seg * 8);
#pragma unroll
            for (int e = 0; e < 8; ++e)
                VT[(seg * 8 + e) * 72 + c] = vv[e];
        }
        __syncthreads();
        f32x4 acco[2][4];
#pragma unroll
        for (int i = 0; i < 2; ++i)
#pragma unroll
            for (int j = 0; j < 4; ++j) acco[i][j] = (f32x4){0.f, 0.f, 0.f, 0.f};
#pragma unroll
        for (int ks = 0; ks < 2; ++ks) {
            bf16x8 pa[2], vb[4];
#pragma unroll
            for (int i = 0; i < 2; ++i)
                pa[i] = *(const bf16x8*)&P[(wm * 32 + i * 16 + (lane & 15)) * 72 + ks * 32 + (lane >> 4) * 8];
#pragma unroll
            for (int j = 0; j < 4; ++j)
                vb[j] = *(const bf16x8*)&VT[(wn * 64 + j * 16 + (lane & 15)) * 72 + ks * 32 + (lane >> 4) * 8];
#pragma unroll
            for (int i = 0; i < 2; ++i)
#pragma unroll
                for (int j = 0; j < 4; ++j)
                    acco[i][j] = __builtin_amdgcn_mfma_f32_16x16x32_bf16(pa[i], vb[j], acco[i][j], 0, 0, 0);
        }
#pragma unroll
        for (int i = 0; i < 2; ++i)
#pragma unroll
            for (int j = 0; j < 4; ++j)
#pragma unroll
                for (int r = 0; r < 4; ++r) {
                    long b = wm * 32 + i * 16 + (lane >> 4) * 4 + r;
                    int d = dc * 128 + wn * 64 + j * 16 + (lane & 15);
                    attn[b * ROWEL + n * 768 + d] = acco[i][j][r];
                }
    }
}

// ---------------- LayerNorm over last dim (768), in place ----------------
__global__ __launch_bounds__(256) void k_ln(float* __restrict__ a,
                                            const float* __restrict__ g, const float* __restrict__ bb)
{
    const long row = blockIdx.x * 4 + (threadIdx.x >> 6);
    const int lane = threadIdx.x & 63;
    float* p = a + row * 768;
    f32x4 xv[3];
    float s = 0.f;
#pragma unroll
    for (int c = 0; c < 3; ++c) {
        xv[c] = *(const f32x4*)(p + c * 256 + lane * 4);
        s += xv[c][0] + xv[c][1] + xv[c][2] + xv[c][3];
    }
#pragma unroll
    for (int o = 1; o < 64; o <<= 1) s += __shfl_xor(s, o);
    const float mu = s * (1.f / 768.f);
    float vs = 0.f;
#pragma unroll
    for (int c = 0; c < 3; ++c)
#pragma unroll
        for (int e = 0; e < 4; ++e) { float d = xv[c][e] - mu; vs += d * d; }
#pragma unroll
    for (int o = 1; o < 64; o <<= 1) vs += __shfl_xor(vs, o);
    const float rstd = rsqrtf(vs * (1.f / 768.f) + 1e-5f);
#pragma unroll
    for (int c = 0; c < 3; ++c)
#pragma unroll
        for (int e = 0; e < 4; ++e) {
            int col = c * 256 + lane * 4 + e;
            p[col] = (xv[c][e] - mu) * rstd * g[col] + bb[col];
        }
}

// ---------------- row softmax over 768, in place ----------------
__global__ __launch_bounds__(256) void k_softmax(float* __restrict__ o)
{
    const long row = blockIdx.x * 4 + (threadIdx.x >> 6);
    const int lane = threadIdx.x & 63;
    float* p = o + row * 768;
    f32x4 xv[3];
    float m = -1e30f;
#pragma unroll
    for (int c = 0; c < 3; ++c) {
        xv[c] = *(const f32x4*)(p + c * 256 + lane * 4);
        m = fmaxf(m, fmaxf(fmaxf(xv[c][0], xv[c][1]), fmaxf(xv[c][2], xv[c][3])));
    }
#pragma unroll
    for (int o2 = 1; o2 < 64; o2 <<= 1) m = fmaxf(m, __shfl_xor(m, o2));
    float s = 0.f;
#pragma unroll
    for (int c = 0; c < 3; ++c)
#pragma unroll
        for (int e = 0; e < 4; ++e) { float ev = __expf(xv[c][e] - m); xv[c][e] = ev; s += ev; }
#pragma unroll
    for (int o2 = 1; o2 < 64; o2 <<= 1) s += __shfl_xor(s, o2);
    const float inv = 1.f / s;
#pragma unroll
    for (int c = 0; c < 3; ++c)
        *(f32x4*)(p + c * 256 + lane * 4) = xv[c] * inv;
}

extern "C" void kernel_launch(void* const* d_in, const int* in_sizes, int n_in,
                              void* d_out, int out_size, void* d_ws, size_t ws_size,
                              hipStream_t stream)
{
    const float* x   = (const float*)d_in[0];
    const float* Wq  = (const float*)d_in[1];
    const float* bq  = (const float*)d_in[2];
    const float* Wk  = (const float*)d_in[3];
    const float* bk  = (const float*)d_in[4];
    const float* Wv  = (const float*)d_in[5];
    const float* bv  = (const float*)d_in[6];
    const float* lng = (const float*)d_in[7];
    const float* lnb = (const float*)d_in[8];
    const float* p1w = (const float*)d_in[9];
    const float* p1b = (const float*)d_in[10];
    const float* w0  = (const float*)d_in[11];
    const float* b0  = (const float*)d_in[12];
    const float* w1  = (const float*)d_in[13];
    const float* b1  = (const float*)d_in[14];
    const float* w2  = (const float*)d_in[15];
    const float* b2  = (const float*)d_in[16];
    const float* w3  = (const float*)d_in[17];
    const float* b3  = (const float*)d_in[18];
    const float* w4  = (const float*)d_in[19];
    const float* b4  = (const float*)d_in[20];
    const float* p2w = (const float*)d_in[21];
    const float* p2b = (const float*)d_in[22];
    float* out = (float*)d_out;

    char* wsbase = (char*)d_ws;
    size_t off = 0;
    auto alloc = [&](size_t bytes) { char* p = wsbase + off; off += (bytes + 255) & ~(size_t)255; return p; };
    bf16*  flat    = (bf16*)alloc(4096L * 768 * 2);
    bf16*  flat_nb = (bf16*)alloc(4096L * 768 * 2);
    bf16*  qb   = (bf16*)alloc(4096L * 768 * 2);
    bf16*  kb   = (bf16*)alloc(4096L * 768 * 2);
    bf16*  vb2  = (bf16*)alloc(4096L * 768 * 2);
    float* attn = (float*)alloc(4096L * 768 * 4);
    bf16*  att  = (bf16*)alloc(4096L * 768 * 2);
    bf16*  p1t  = (bf16*)alloc(768L * 768 * 2);
    bf16*  w4t  = (bf16*)alloc(768L * 3072 * 2);
    bf16*  w0c  = (bf16*)alloc(768L * 3072 * 2);
    bf16*  w1c  = (bf16*)alloc(3072L * 3072 * 2);
    bf16*  w2c  = (bf16*)alloc(3072L * 3072 * 2);
    bf16*  w3c  = (bf16*)alloc(3072L * 3072 * 2);
    bf16*  M1   = (bf16*)alloc(768L * 3072 * 2);
    bf16*  M2   = (bf16*)alloc(768L * 3072 * 2);
    bf16*  M3   = (bf16*)alloc(768L * 3072 * 2);
    bf16*  Mt   = (bf16*)alloc(768L * 768 * 2);
    float* Cp   = (float*)alloc(4L * 768 * 3072 * 4);   // split-K partials (reused)
    float* vPa  = (float*)alloc(8L * 3072 * 4);
    float* vPb  = (float*)alloc(8L * 3072 * 4);
    float* c4   = (float*)alloc(768 * 4);
    if (off > ws_size) return;

    const long ZS  = 768L * 3072;    // partial stride steps 1-3
    const long ZS4 = 768L * 768;     // partial stride step 4

    // ---- prep ----
    k_patchify<<<dim3(64, 64), 256, 0, stream>>>(x, flat, flat_nb);
    k_cast4<<<dim3(4608, 4), 256, 0, stream>>>(w0, w0c, w1, w1c, w2, w2c, w3, w3c);
    k_cvt_t2<<<dim3(48, 12, 2), 256, 0, stream>>>(w4, w4t, p1w, p1t);

    // ---- QKV (XCD-grouped 1-D grid, patch-major A) ----
    k_qkv<<<2304, 256, 0, stream>>>(flat_nb, Wq, Wk, Wv, bq, bk, bv, qb, kb, vb2);

    k_attn<<<dim3(6, 64), 256, 0, stream>>>(qb, kb, vb2, attn);
    k_ln<<<1024, 256, 0, stream>>>(attn, lng, lnb);
    // att = ln + flat @ p1_w + p1_b -> bf16
    k_gemm_rs<64, 64><<<dim3(64, 12), 256, 0, stream>>>(flat, 768, p1t, 768, 768, p1b, attn, att, nullptr, 768);

    // ---- weight collapse (split-K 2): Mt[n][k] = (w0..w4)[k][n] + p2w[k][n] ----
    k_chainrs<<<dim3(12, 48, 2), 256, 0, stream>>>(w4t, 3072, w3c, 3072, 1536, Cp, ZS, 3072);
    k_skadd<<<2304, 256, 0, stream>>>(Cp, ZS, 2, ZS, M1);
    k_chainrs<<<dim3(12, 48, 2), 256, 0, stream>>>(M1, 3072, w2c, 3072, 1536, Cp, ZS, 3072);
    k_skadd<<<2304, 256, 0, stream>>>(Cp, ZS, 2, ZS, M2);
    k_chainrs<<<dim3(12, 48, 2), 256, 0, stream>>>(M2, 3072, w1c, 3072, 1536, Cp, ZS, 3072);
    k_skadd<<<2304, 256, 0, stream>>>(Cp, ZS, 2, ZS, M3);
    k_chainrs<<<dim3(12, 12, 4), 256, 0, stream>>>(M3, 3072, w0c, 3072, 768, Cp, ZS4, 768);
    k_skaddT<<<768, 256, 0, stream>>>(Cp, ZS4, 4, p2w, Mt);

    // ---- bias chain ----
    k_vm2<bf16><<<dim3(48, 8), 256, 0, stream>>>(nullptr, b0, w1c, 3072, 3072, vPa);
    k_vm2<bf16><<<dim3(48, 8), 256, 0, stream>>>(vPa, b1, w2c, 3072, 3072, vPb);
    k_vm2<bf16><<<dim3(48, 8), 256, 0, stream>>>(vPb, b2, w3c, 3072, 3072, vPa);
    k_vm2<float><<<dim3(12, 8), 256, 0, stream>>>(vPa, b3, w4, 3072, 768, vPb);
    k_vred<<<3, 256, 0, stream>>>(vPb, b4, p2b, 768, c4);

    // ---- out = att @ (M + p2w) + c ----
    k_gemm_rs<64, 64><<<dim3(64, 12), 256, 0, stream>>>(att, 768, Mt, 768, 768, c4, nullptr, nullptr, out, 768);
    k_softmax<<<1024, 256, 0, stream>>>(out);
}